// Round 10
// baseline (134.759 us; speedup 1.0000x reference)
//
#include <hip/hip_runtime.h>

#define N_NODES 50000
#define N_EDGES 800000
#define D 128
#define NBUCK 196             // ceil(50000/256) dst buckets of 256 nodes
#define CAP 8192              // edges capacity per bucket region (mean 4096, sd 64)
#define WT_LD 136             // 128 + 8 fp16 pad (272B row stride, bank-spread)
#define PLANE_HALVES 1600000  // 50000 nodes * 32 halves (64B/row) = 3.2 MB/plane
#define AGG_NODES 64          // nodes per agg block (64 | 256 -> single bucket span)
#define AGG_LDS 2048          // staged edge indices (sum of 64 Poisson(16) degs << 2048)

typedef float    f32x4 __attribute__((ext_vector_type(4)));
typedef float    f32x2 __attribute__((ext_vector_type(2)));
typedef _Float16 f16x2 __attribute__((ext_vector_type(2)));
typedef _Float16 half8 __attribute__((ext_vector_type(8)));

__device__ inline half8 cvt8(const float* __restrict__ p) {
    f32x4 a = *(const f32x4*)p;
    f32x4 b = *(const f32x4*)(p + 4);
    half8 r;
    r[0] = (_Float16)a.x; r[1] = (_Float16)a.y; r[2] = (_Float16)a.z; r[3] = (_Float16)a.w;
    r[4] = (_Float16)b.x; r[5] = (_Float16)b.y; r[6] = (_Float16)b.z; r[7] = (_Float16)b.w;
    return r;
}

// ---------- graph build: two-phase LDS counting sort ----------

// Phase A: bucket edges by dst>>8 into fixed-capacity regions.
// Record = src | (dstlocal<<16); src < 50000 < 2^16, dstlocal < 256.
__global__ __launch_bounds__(256) void k_bucket(const int* __restrict__ ei,
                                                int* __restrict__ gcur,
                                                int* __restrict__ pk) {
    __shared__ int lcnt[NBUCK];
    __shared__ int lbase[NBUCK];
    const int t = threadIdx.x;
    for (int i = t; i < NBUCK; i += 256) lcnt[i] = 0;
    __syncthreads();

    const int base = blockIdx.x * 2048;
    int  vals[8], bks[8], rks[8];
    bool ok[8];
#pragma unroll
    for (int u = 0; u < 8; ++u) {
        int e = base + u * 256 + t;
        ok[u] = (e < N_EDGES);
        if (ok[u]) {
            int s = ei[e];
            int d = ei[N_EDGES + e];
            bks[u]  = d >> 8;
            vals[u] = s | ((d & 255) << 16);
            rks[u]  = atomicAdd(&lcnt[bks[u]], 1);
        }
    }
    __syncthreads();
    for (int i = t; i < NBUCK; i += 256)
        lbase[i] = lcnt[i] ? atomicAdd(&gcur[i], lcnt[i]) : 0;
    __syncthreads();
#pragma unroll
    for (int u = 0; u < 8; ++u)
        if (ok[u])
            pk[bks[u] * CAP + lbase[bks[u]] + rks[u]] = vals[u];
}

// Phase B: one block per bucket. LDS hist over 256 dsts -> scan -> rowstart/
// rowcnt/dinv; stable-place esrc in LDS staging, write out coalesced.
__global__ __launch_bounds__(256) void k_csr(const int* __restrict__ gcur,
                                             const int* __restrict__ pk,
                                             int* __restrict__ rowstart,
                                             int* __restrict__ rowcnt,
                                             float* __restrict__ dinv,
                                             int* __restrict__ esrc) {
    __shared__ int hcnt[256];
    __shared__ int sbase[256];
    __shared__ int lcur[256];
    __shared__ int sd[256];
    __shared__ int lesrc[CAP];

    const int b  = blockIdx.x;
    const int t  = threadIdx.x;
    const int RB = b * CAP;
    const int nb = gcur[b];

    hcnt[t] = 0;
    lcur[t] = 0;
    __syncthreads();
    for (int i = t; i < nb; i += 256) {
        int dl = (pk[RB + i] >> 16) & 255;
        atomicAdd(&hcnt[dl], 1);
    }
    __syncthreads();

    // exclusive scan of hcnt
    int v = hcnt[t];
    sd[t] = v;
    __syncthreads();
    for (int off = 1; off < 256; off <<= 1) {
        int u = (t >= off) ? sd[t - off] : 0;
        __syncthreads();
        sd[t] += u;
        __syncthreads();
    }
    sbase[t] = sd[t] - v;
    __syncthreads();

    int g = b * 256 + t;
    if (g < N_NODES) {
        rowstart[g] = RB + sbase[t];
        rowcnt[g]   = v;
        dinv[g]     = rsqrtf((float)v + 1.0f);   // +1 self-loop
    }

    for (int i = t; i < nb; i += 256) {
        int val = pk[RB + i];
        int dl  = (val >> 16) & 255;
        int r   = atomicAdd(&lcur[dl], 1);
        lesrc[sbase[dl] + r] = val & 0xFFFF;
    }
    __syncthreads();
    for (int i = t; i < nb; i += 256)
        esrc[RB + i] = lesrc[i];
}

// ---------- dense transform via MFMA: H' = fp16( (X @ W) * dinv[row] ) ----------
// 256 threads = 4 waves, 64 rows/block. W^T fp16 in LDS once; 32 B-frags in
// VGPRs; A straight from global; C restaged through LDS, written as 4 CHUNK
// PLANES: plane c holds cols [32c,32c+32) of every node row (64B/row, 3.2 MB
// /plane -> fits one XCD L2). gemm2 A-frag t == plane t.
// Frag maps: A lane l -> row=l&15, k=(l>>4)*8+j ; B lane l -> col=l&15, same k;
// C/D lane l -> col=l&15, row=(l>>4)*4+reg (verified m89 layout).

template <typename XT>
__global__ __launch_bounds__(256) void k_gemm(const XT* __restrict__ X,
                                              const float* __restrict__ W,
                                              const float* __restrict__ dinv,
                                              _Float16* __restrict__ H) {
    __shared__ __align__(16) _Float16 WT[128 * WT_LD];   // 34 KiB; reused for C staging

    const int tid  = threadIdx.x;
    const int base = blockIdx.x * 64;
    const int w    = tid >> 6;          // wave 0..3
    const int lane = tid & 63;
    const int c    = lane & 15;         // row (A) / col (B,C)
    const int g    = lane >> 4;         // k-group

    // stage W^T as fp16: WT[col][k]
    for (int idx = tid; idx < 128 * 128; idx += 256) {
        int k = idx >> 7, cc = idx & 127;
        WT[cc * WT_LD + k] = (_Float16)W[idx];
    }
    __syncthreads();

    // B-frags to registers: bf[n][t] = W[k = t*32+g*8 .. +8][col = n*16+c]
    half8 bf[8][4];
#pragma unroll
    for (int n = 0; n < 8; ++n)
#pragma unroll
        for (int t = 0; t < 4; ++t)
            bf[n][t] = *(const half8*)&WT[(n * 16 + c) * WT_LD + t * 32 + g * 8];
    __syncthreads();                     // all reads of WT done before C reuses it

    // A-frags straight from global (f32 row-major layer 1, fp16 planes layer 2)
    int rowA = base + w * 16 + c;
    if (rowA >= N_NODES) rowA = N_NODES - 1;       // clamp; tail rows never stored
    half8 af[4];
#pragma unroll
    for (int t = 0; t < 4; ++t) {
        if constexpr (sizeof(XT) == 2)
            af[t] = *(const half8*)(X + (size_t)t * PLANE_HALVES + (size_t)rowA * 32 + g * 8);
        else
            af[t] = cvt8((const float*)X + (size_t)rowA * D + t * 32 + g * 8);
    }

    f32x4 acc[8];
#pragma unroll
    for (int n = 0; n < 8; ++n) acc[n] = (f32x4)0.f;
#pragma unroll
    for (int t = 0; t < 4; ++t)
#pragma unroll
        for (int n = 0; n < 8; ++n)
            acc[n] = __builtin_amdgcn_mfma_f32_16x16x32_f16(af[t], bf[n][t], acc[n], 0, 0, 0);

    // epilogue: scale by dinv, drop to fp16 via LDS, write 4 chunk planes
    float dv[4];
#pragma unroll
    for (int j = 0; j < 4; ++j) {
        int rr = base + w * 16 + g * 4 + j;
        dv[j] = dinv[rr < N_NODES ? rr : N_NODES - 1];
    }
#pragma unroll
    for (int n = 0; n < 8; ++n)
#pragma unroll
        for (int j = 0; j < 4; ++j)
            WT[(w * 16 + g * 4 + j) * WT_LD + n * 16 + c] = (_Float16)(acc[n][j] * dv[j]);
    __syncthreads();

#pragma unroll
    for (int ch = 0; ch < 4; ++ch) {
        int r   = tid >> 2;            // 64 rows
        int sub = tid & 3;             // 4 x 16B per 64B plane row
        int gr  = base + r;
        if (gr < N_NODES)
            *(half8*)(H + (size_t)ch * PLANE_HALVES + (size_t)gr * 32 + sub * 8)
                = *(const half8*)&WT[r * WT_LD + ch * 32 + sub * 8];
    }
}

// ---------- aggregation: out[n] = dinv[n]*(h'[n] + sum_e h'[src]) + b ----------
// Chunk-plane partitioned (block handles chunk bid&3; plane 3.2 MB stays
// L2-resident on its XCDs -> every gather is one local 64B line). R8's defect
// fixed: the block's 64 nodes share ONE contiguous esrc span (bucket-sorted),
// coalesce-staged into LDS once -> per-group serial NT index loads eliminated;
// indices come from free same-address LDS broadcasts. Pairwise f16x2 pre-add
// halves the convert/add stream. 16-lane groups, 4 nodes sequential per group.

template <int RELU, typename OT>
__global__ __launch_bounds__(256) void k_agg(const _Float16* __restrict__ Hq,
                                             const int* __restrict__ rowstart,
                                             const int* __restrict__ rowcnt,
                                             const int* __restrict__ esrc,
                                             const float* __restrict__ dinv,
                                             const float* __restrict__ bias,
                                             OT* __restrict__ OUT) {
    __shared__ int lesrc[AGG_LDS];
    const int chunk = blockIdx.x & 3;
    const int n0    = (blockIdx.x >> 2) * AGG_NODES;
    const int t     = threadIdx.x;
    const int g     = t >> 4;
    const int l     = t & 15;
    const _Float16* P = Hq + (size_t)chunk * PLANE_HALVES;

    // stage the block's contiguous edge-index span (NT: don't evict the plane)
    int last = n0 + AGG_NODES - 1;
    if (last >= N_NODES) last = N_NODES - 1;
    const int start = rowstart[n0];
    const int span  = rowstart[last] + rowcnt[last] - start;
    for (int i = t; i < span; i += 256)
        lesrc[i] = __builtin_nontemporal_load(&esrc[start + i]);
    __syncthreads();

#pragma unroll
    for (int u = 0; u < 4; ++u) {
        int node = n0 + g * 4 + u;
        if (node < N_NODES) {
            float di = dinv[node];
            f16x2 h0 = *(const f16x2*)(P + (size_t)node * 32 + l * 2);
            float a0 = (float)h0.x, a1 = (float)h0.y;      // self-loop term

            int ls  = rowstart[node] - start;
            int cnt = rowcnt[node];
            int j = 0;
            for (; j + 7 < cnt; j += 8) {
                int s0 = lesrc[ls + j];
                int s1 = lesrc[ls + j + 1];
                int s2 = lesrc[ls + j + 2];
                int s3 = lesrc[ls + j + 3];
                int s4 = lesrc[ls + j + 4];
                int s5 = lesrc[ls + j + 5];
                int s6 = lesrc[ls + j + 6];
                int s7 = lesrc[ls + j + 7];
                f16x2 v0 = *(const f16x2*)(P + (size_t)s0 * 32 + l * 2);
                f16x2 v1 = *(const f16x2*)(P + (size_t)s1 * 32 + l * 2);
                f16x2 v2 = *(const f16x2*)(P + (size_t)s2 * 32 + l * 2);
                f16x2 v3 = *(const f16x2*)(P + (size_t)s3 * 32 + l * 2);
                f16x2 v4 = *(const f16x2*)(P + (size_t)s4 * 32 + l * 2);
                f16x2 v5 = *(const f16x2*)(P + (size_t)s5 * 32 + l * 2);
                f16x2 v6 = *(const f16x2*)(P + (size_t)s6 * 32 + l * 2);
                f16x2 v7 = *(const f16x2*)(P + (size_t)s7 * 32 + l * 2);
                f16x2 p01 = v0 + v1, p23 = v2 + v3, p45 = v4 + v5, p67 = v6 + v7;
                a0 += ((float)p01.x + (float)p23.x) + ((float)p45.x + (float)p67.x);
                a1 += ((float)p01.y + (float)p23.y) + ((float)p45.y + (float)p67.y);
            }
            for (; j + 1 < cnt; j += 2) {
                int s0 = lesrc[ls + j];
                int s1 = lesrc[ls + j + 1];
                f16x2 v0 = *(const f16x2*)(P + (size_t)s0 * 32 + l * 2);
                f16x2 v1 = *(const f16x2*)(P + (size_t)s1 * 32 + l * 2);
                f16x2 p = v0 + v1;
                a0 += (float)p.x;
                a1 += (float)p.y;
            }
            if (j < cnt) {
                int s0 = lesrc[ls + j];
                f16x2 v0 = *(const f16x2*)(P + (size_t)s0 * 32 + l * 2);
                a0 += (float)v0.x;
                a1 += (float)v0.y;
            }

            f32x2 bv = *(const f32x2*)(bias + chunk * 32 + l * 2);
            float r0 = a0 * di + bv.x;
            float r1 = a1 * di + bv.y;
            if (RELU) {
                r0 = fmaxf(r0, 0.f);
                r1 = fmaxf(r1, 0.f);
            }
            if constexpr (sizeof(OT) == 2) {
                // fp16 chunk-plane output (consumed by gemm2's plane A-loads)
                f16x2 o;
                o.x = (_Float16)r0; o.y = (_Float16)r1;
                *(f16x2*)((_Float16*)OUT + (size_t)chunk * PLANE_HALVES
                          + (size_t)node * 32 + l * 2) = o;
            } else {
                // f32 row-major final output
                f32x2 o;
                o.x = r0; o.y = r1;
                __builtin_nontemporal_store(
                    o, (f32x2*)((float*)OUT + (size_t)node * D + chunk * 32 + l * 2));
            }
        }
    }
}

// ---------- launch ----------

extern "C" void kernel_launch(void* const* d_in, const int* in_sizes, int n_in,
                              void* d_out, int out_size, void* d_ws, size_t ws_size,
                              hipStream_t stream) {
    const float* x  = (const float*)d_in[0];
    const int*   ei = (const int*)d_in[1];
    const float* W1 = (const float*)d_in[2];
    const float* b1 = (const float*)d_in[3];
    const float* W2 = (const float*)d_in[4];
    const float* b2 = (const float*)d_in[5];
    float* out = (float*)d_out;

    // ws layout (4B units; regions padded for 16B alignment)
    int*      gcur     = (int*)d_ws;                    // 256 (196 used)
    int*      rowstart = gcur + 256;                    // 50048
    int*      rowcnt   = rowstart + 50048;              // 50048
    float*    dinv     = (float*)(rowcnt + 50048);      // 50048
    int*      pk       = (int*)(dinv + 50048);          // 196*8192 = 1,605,632
    int*      esrc     = pk + NBUCK * CAP;              // 1,605,632
    _Float16* h1       = (_Float16*)(esrc + NBUCK * CAP); // 4 planes = 6.4M halves
    _Float16* ag16     = h1 + 4 * PLANE_HALVES;         // 4 planes
    _Float16* h2       = ag16 + 4 * PLANE_HALVES;       // 4 planes

    const int TB  = 256;
    const int gbB = (N_EDGES + 2047) / 2048;             // 391 bucket blocks
    const int gbG = (N_NODES + 63) / 64;                 // 782 gemm blocks
    const int gbA = 4 * ((N_NODES + AGG_NODES - 1) / AGG_NODES);   // 4*782 agg blocks

    // graph build (shared by both layers): zero cursors -> bucket -> CSR
    hipMemsetAsync(gcur, 0, NBUCK * sizeof(int), stream);
    k_bucket<<<gbB, TB, 0, stream>>>(ei, gcur, pk);
    k_csr<<<NBUCK, TB, 0, stream>>>(gcur, pk, rowstart, rowcnt, dinv, esrc);

    // layer 1
    k_gemm<float><<<gbG, TB, 0, stream>>>(x, W1, dinv, h1);
    k_agg<1, _Float16><<<gbA, TB, 0, stream>>>(h1, rowstart, rowcnt, esrc, dinv, b1, ag16);
    // layer 2
    k_gemm<_Float16><<<gbG, TB, 0, stream>>>(ag16, W2, dinv, h2);
    k_agg<0, float><<<gbA, TB, 0, stream>>>(h2, rowstart, rowcnt, esrc, dinv, b2, out);
}

// Round 11
// 125.176 us; speedup vs baseline: 1.0766x; 1.0766x over previous
//
#include <hip/hip_runtime.h>

#define N_NODES 50000
#define N_EDGES 800000
#define D 128
#define NBUCK 196             // ceil(50000/256) dst buckets of 256 nodes
#define CAP 8192              // edges capacity per bucket region (mean 4096, sd 64)
#define WT_LD 136             // 128 + 8 fp16 pad (272B row stride, bank-spread)

typedef float    f32x4 __attribute__((ext_vector_type(4)));
typedef _Float16 f16x4 __attribute__((ext_vector_type(4)));
typedef _Float16 half8 __attribute__((ext_vector_type(8)));

__device__ inline f32x4 cvt4(f16x4 h) {
    f32x4 r;
    r.x = (float)h.x; r.y = (float)h.y; r.z = (float)h.z; r.w = (float)h.w;
    return r;
}

__device__ inline half8 cvt8(const float* __restrict__ p) {
    f32x4 a = *(const f32x4*)p;
    f32x4 b = *(const f32x4*)(p + 4);
    half8 r;
    r[0] = (_Float16)a.x; r[1] = (_Float16)a.y; r[2] = (_Float16)a.z; r[3] = (_Float16)a.w;
    r[4] = (_Float16)b.x; r[5] = (_Float16)b.y; r[6] = (_Float16)b.z; r[7] = (_Float16)b.w;
    return r;
}

// ---------- graph build: two-phase LDS counting sort ----------

__global__ void k_zero(int* __restrict__ p, int n) {
    int i = blockIdx.x * blockDim.x + threadIdx.x;
    if (i < n) p[i] = 0;
}

// Phase A: bucket edges by dst>>8 into fixed-capacity regions.
// Record = src | (dstlocal<<16); src < 50000 < 2^16, dstlocal < 256.
__global__ __launch_bounds__(256) void k_bucket(const int* __restrict__ ei,
                                                int* __restrict__ gcur,
                                                int* __restrict__ pk) {
    __shared__ int lcnt[NBUCK];
    __shared__ int lbase[NBUCK];
    const int t = threadIdx.x;
    for (int i = t; i < NBUCK; i += 256) lcnt[i] = 0;
    __syncthreads();

    const int base = blockIdx.x * 2048;
    int  vals[8], bks[8], rks[8];
    bool ok[8];
#pragma unroll
    for (int u = 0; u < 8; ++u) {
        int e = base + u * 256 + t;
        ok[u] = (e < N_EDGES);
        if (ok[u]) {
            int s = ei[e];
            int d = ei[N_EDGES + e];
            bks[u]  = d >> 8;
            vals[u] = s | ((d & 255) << 16);
            rks[u]  = atomicAdd(&lcnt[bks[u]], 1);
        }
    }
    __syncthreads();
    for (int i = t; i < NBUCK; i += 256)
        lbase[i] = lcnt[i] ? atomicAdd(&gcur[i], lcnt[i]) : 0;
    __syncthreads();
#pragma unroll
    for (int u = 0; u < 8; ++u)
        if (ok[u])
            pk[bks[u] * CAP + lbase[bks[u]] + rks[u]] = vals[u];
}

// Phase B: one block per bucket. LDS hist over 256 dsts -> scan -> rowstart/
// rowcnt/dinv; stable-place esrc in LDS staging, write out coalesced.
__global__ __launch_bounds__(256) void k_csr(const int* __restrict__ gcur,
                                             const int* __restrict__ pk,
                                             int* __restrict__ rowstart,
                                             int* __restrict__ rowcnt,
                                             float* __restrict__ dinv,
                                             int* __restrict__ esrc) {
    __shared__ int hcnt[256];
    __shared__ int sbase[256];
    __shared__ int lcur[256];
    __shared__ int sd[256];
    __shared__ int lesrc[CAP];

    const int b  = blockIdx.x;
    const int t  = threadIdx.x;
    const int RB = b * CAP;
    const int nb = gcur[b];

    hcnt[t] = 0;
    lcur[t] = 0;
    __syncthreads();
    for (int i = t; i < nb; i += 256) {
        int dl = (pk[RB + i] >> 16) & 255;
        atomicAdd(&hcnt[dl], 1);
    }
    __syncthreads();

    // exclusive scan of hcnt
    int v = hcnt[t];
    sd[t] = v;
    __syncthreads();
    for (int off = 1; off < 256; off <<= 1) {
        int u = (t >= off) ? sd[t - off] : 0;
        __syncthreads();
        sd[t] += u;
        __syncthreads();
    }
    sbase[t] = sd[t] - v;
    __syncthreads();

    int g = b * 256 + t;
    if (g < N_NODES) {
        rowstart[g] = RB + sbase[t];
        rowcnt[g]   = v;
        dinv[g]     = rsqrtf((float)v + 1.0f);   // +1 self-loop
    }

    for (int i = t; i < nb; i += 256) {
        int val = pk[RB + i];
        int dl  = (val >> 16) & 255;
        int r   = atomicAdd(&lcur[dl], 1);
        lesrc[sbase[dl] + r] = val & 0xFFFF;
    }
    __syncthreads();
    for (int i = t; i < nb; i += 256)
        esrc[RB + i] = lesrc[i];
}

// ---------- dense transform via MFMA: H' = fp16( (X @ W) * dinv[row] ) ----------
// 256 threads = 4 waves, 64 rows/block. W^T fp16 in LDS once; 32 B-frags in
// VGPRs; A straight from global; C restaged through LDS for coalesced row-major
// fp16 stores. Frag maps: A lane l -> row=l&15, k=(l>>4)*8+j ; B lane l ->
// col=l&15, same k; C/D lane l -> col=l&15, row=(l>>4)*4+reg (m89 layout).

template <typename XT>
__global__ __launch_bounds__(256) void k_gemm(const XT* __restrict__ X,
                                              const float* __restrict__ W,
                                              const float* __restrict__ dinv,
                                              _Float16* __restrict__ H) {
    __shared__ __align__(16) _Float16 WT[128 * WT_LD];   // 34 KiB; reused for C staging

    const int tid  = threadIdx.x;
    const int base = blockIdx.x * 64;
    const int w    = tid >> 6;          // wave 0..3
    const int lane = tid & 63;
    const int c    = lane & 15;         // row (A) / col (B,C)
    const int g    = lane >> 4;         // k-group

    // stage W^T as fp16: WT[col][k]
    for (int idx = tid; idx < 128 * 128; idx += 256) {
        int k = idx >> 7, cc = idx & 127;
        WT[cc * WT_LD + k] = (_Float16)W[idx];
    }
    __syncthreads();

    // B-frags to registers: bf[n][t] = W[k = t*32+g*8 .. +8][col = n*16+c]
    half8 bf[8][4];
#pragma unroll
    for (int n = 0; n < 8; ++n)
#pragma unroll
        for (int t = 0; t < 4; ++t)
            bf[n][t] = *(const half8*)&WT[(n * 16 + c) * WT_LD + t * 32 + g * 8];
    __syncthreads();                     // all reads of WT done before C reuses it

    // A-frags straight from global
    int rowA = base + w * 16 + c;
    if (rowA >= N_NODES) rowA = N_NODES - 1;       // clamp; tail rows never stored
    half8 af[4];
#pragma unroll
    for (int t = 0; t < 4; ++t) {
        if constexpr (sizeof(XT) == 2)
            af[t] = *(const half8*)(X + (size_t)rowA * D + t * 32 + g * 8);
        else
            af[t] = cvt8((const float*)X + (size_t)rowA * D + t * 32 + g * 8);
    }

    f32x4 acc[8];
#pragma unroll
    for (int n = 0; n < 8; ++n) acc[n] = (f32x4)0.f;
#pragma unroll
    for (int t = 0; t < 4; ++t)
#pragma unroll
        for (int n = 0; n < 8; ++n)
            acc[n] = __builtin_amdgcn_mfma_f32_16x16x32_f16(af[t], bf[n][t], acc[n], 0, 0, 0);

    // epilogue: scale by dinv, drop to fp16 via LDS for coalesced stores
    float dv[4];
#pragma unroll
    for (int j = 0; j < 4; ++j) {
        int rr = base + w * 16 + g * 4 + j;
        dv[j] = dinv[rr < N_NODES ? rr : N_NODES - 1];
    }
#pragma unroll
    for (int n = 0; n < 8; ++n)
#pragma unroll
        for (int j = 0; j < 4; ++j)
            WT[(w * 16 + g * 4 + j) * WT_LD + n * 16 + c] = (_Float16)(acc[n][j] * dv[j]);
    __syncthreads();

    for (int idx = tid; idx < 64 * 16; idx += 256) {   // 64 rows x 16 chunks of 8 fp16
        int r = idx >> 4, ch = idx & 15;
        int gr = base + r;
        if (gr < N_NODES)
            *(half8*)(H + (size_t)gr * D + ch * 8) = *(const half8*)&WT[r * WT_LD + ch * 8];
    }
}

// ---------- aggregation: out[n] = dinv[n]*(h'[n] + sum_e h'[src]) + b ----------
// 32 lanes per node (f16x4 = 8 B/lane, 256 B/row = 4 cache lines per edge).
// Coalesced 32-wide edge-index load + __shfl broadcast; 8 row-gathers in flight.

template <int RELU, typename OT>
__global__ __launch_bounds__(256) void k_agg(const _Float16* __restrict__ Hs,
                                             const int* __restrict__ rowstart,
                                             const int* __restrict__ rowcnt,
                                             const int* __restrict__ esrc,
                                             const float* __restrict__ dinv,
                                             const float* __restrict__ bias,
                                             OT* __restrict__ OUT) {
    int node = blockIdx.x * 8 + (threadIdx.x >> 5);
    int lane = threadIdx.x & 31;
    const f16x4* Hv = (const f16x4*)Hs;

    float di = dinv[node];
    f32x4 acc = cvt4(Hv[(size_t)node * 32 + lane]);   // h'[n] (self-loop term)

    int s   = __builtin_nontemporal_load(&rowstart[node]);
    int cnt = __builtin_nontemporal_load(&rowcnt[node]);
    int e   = s + cnt;
    for (int off = s; off < e; off += 32) {
        int n = e - off;
        if (n > 32) n = 32;
        int idx  = off + (lane < n ? lane : n - 1);   // clamp: no OOB reads
        int eidx = __builtin_nontemporal_load(&esrc[idx]);
        int j = 0;
        for (; j + 7 < n; j += 8) {
            int s0 = __shfl(eidx, j,     32);
            int s1 = __shfl(eidx, j + 1, 32);
            int s2 = __shfl(eidx, j + 2, 32);
            int s3 = __shfl(eidx, j + 3, 32);
            int s4 = __shfl(eidx, j + 4, 32);
            int s5 = __shfl(eidx, j + 5, 32);
            int s6 = __shfl(eidx, j + 6, 32);
            int s7 = __shfl(eidx, j + 7, 32);
            f16x4 v0 = Hv[(size_t)s0 * 32 + lane];
            f16x4 v1 = Hv[(size_t)s1 * 32 + lane];
            f16x4 v2 = Hv[(size_t)s2 * 32 + lane];
            f16x4 v3 = Hv[(size_t)s3 * 32 + lane];
            f16x4 v4 = Hv[(size_t)s4 * 32 + lane];
            f16x4 v5 = Hv[(size_t)s5 * 32 + lane];
            f16x4 v6 = Hv[(size_t)s6 * 32 + lane];
            f16x4 v7 = Hv[(size_t)s7 * 32 + lane];
            acc += ((cvt4(v0) + cvt4(v1)) + (cvt4(v2) + cvt4(v3)))
                 + ((cvt4(v4) + cvt4(v5)) + (cvt4(v6) + cvt4(v7)));
        }
        for (; j + 3 < n; j += 4) {
            int s0 = __shfl(eidx, j,     32);
            int s1 = __shfl(eidx, j + 1, 32);
            int s2 = __shfl(eidx, j + 2, 32);
            int s3 = __shfl(eidx, j + 3, 32);
            f16x4 v0 = Hv[(size_t)s0 * 32 + lane];
            f16x4 v1 = Hv[(size_t)s1 * 32 + lane];
            f16x4 v2 = Hv[(size_t)s2 * 32 + lane];
            f16x4 v3 = Hv[(size_t)s3 * 32 + lane];
            acc += (cvt4(v0) + cvt4(v1)) + (cvt4(v2) + cvt4(v3));
        }
        for (; j < n; ++j) {
            int s0 = __shfl(eidx, j, 32);
            acc += cvt4(Hv[(size_t)s0 * 32 + lane]);
        }
    }

    f32x4 b = ((const f32x4*)bias)[lane];
    f32x4 r = acc * di + b;
    if (RELU) {
        r.x = fmaxf(r.x, 0.f);
        r.y = fmaxf(r.y, 0.f);
        r.z = fmaxf(r.z, 0.f);
        r.w = fmaxf(r.w, 0.f);
    }
    if constexpr (sizeof(OT) == 2) {
        f16x4 o;
        o.x = (_Float16)r.x; o.y = (_Float16)r.y;
        o.z = (_Float16)r.z; o.w = (_Float16)r.w;
        __builtin_nontemporal_store(o, (f16x4*)OUT + (size_t)node * 32 + lane);
    } else {
        __builtin_nontemporal_store(r, (f32x4*)OUT + (size_t)node * 32 + lane);
    }
}

// ---------- launch ----------

extern "C" void kernel_launch(void* const* d_in, const int* in_sizes, int n_in,
                              void* d_out, int out_size, void* d_ws, size_t ws_size,
                              hipStream_t stream) {
    const float* x  = (const float*)d_in[0];
    const int*   ei = (const int*)d_in[1];
    const float* W1 = (const float*)d_in[2];
    const float* b1 = (const float*)d_in[3];
    const float* W2 = (const float*)d_in[4];
    const float* b2 = (const float*)d_in[5];
    float* out = (float*)d_out;

    // ws layout (4B units; regions padded for 16B alignment)
    int*      gcur     = (int*)d_ws;                    // 256 (196 used)
    int*      rowstart = gcur + 256;                    // 50048
    int*      rowcnt   = rowstart + 50048;              // 50048
    float*    dinv     = (float*)(rowcnt + 50048);      // 50048
    int*      pk       = (int*)(dinv + 50048);          // 196*8192 = 1,605,632
    int*      esrc     = pk + NBUCK * CAP;              // 1,605,632
    _Float16* h1       = (_Float16*)(esrc + NBUCK * CAP); // 6.4M halves (12.8 MB)
    _Float16* ag16     = h1 + 6400000;                  // 6.4M halves
    _Float16* h2       = ag16 + 6400000;                // 6.4M halves

    const int TB  = 256;
    const int gbB = (N_EDGES + 2047) / 2048;     // 391 bucket blocks
    const int gbG = (N_NODES + 63) / 64;         // 782 gemm blocks

    // graph build (shared by both layers): zero cursors -> bucket -> CSR
    k_zero<<<1, TB, 0, stream>>>(gcur, NBUCK);
    k_bucket<<<gbB, TB, 0, stream>>>(ei, gcur, pk);
    k_csr<<<NBUCK, TB, 0, stream>>>(gcur, pk, rowstart, rowcnt, dinv, esrc);

    // layer 1
    k_gemm<float><<<gbG, TB, 0, stream>>>(x, W1, dinv, h1);
    k_agg<1, _Float16><<<N_NODES / 8, TB, 0, stream>>>(h1, rowstart, rowcnt, esrc, dinv, b1, ag16);
    // layer 2
    k_gemm<_Float16><<<gbG, TB, 0, stream>>>(ag16, W2, dinv, h2);
    k_agg<0, float><<<N_NODES / 8, TB, 0, stream>>>(h2, rowstart, rowcnt, esrc, dinv, b2, out);
}